// Round 6
// baseline (107.921 us; speedup 1.0000x reference)
//
#include <hip/hip_runtime.h>
#include <stdint.h>
#include <stddef.h>

#define B_ 4
#define T_ 1024
#define D_ 512
#define H_ 8
#define DK_ 64
#define L_ 2047
#define LP_ 2048

typedef __attribute__((ext_vector_type(8))) short short8;
typedef __attribute__((ext_vector_type(4))) short short4_t;
typedef __attribute__((ext_vector_type(4))) float f32x4;
typedef __attribute__((ext_vector_type(4))) unsigned int u32x4;
typedef __attribute__((ext_vector_type(8))) __bf16 bf16x8;

static __device__ __forceinline__ short f2bf(float f) {
  union { float f; unsigned u; } x; x.f = f;
  unsigned r = x.u + 0x7fffu + ((x.u >> 16) & 1u);  // RNE
  return (short)(r >> 16);
}

// packed f32x2 -> bf16x2 (RNE), hw instruction
static __device__ __forceinline__ unsigned cvtpk(float lo, float hi) {
  unsigned r;
  asm("v_cvt_pk_bf16_f32 %0, %1, %2" : "=v"(r) : "v"(lo), "v"(hi));
  return r;
}

static __device__ __forceinline__ f32x4 mfma16(bf16x8 a, bf16x8 b, f32x4 c) {
  return __builtin_amdgcn_mfma_f32_16x16x32_bf16(a, b, c, 0, 0, 0);
}

static __device__ __forceinline__ bf16x8 ldbf8(const short* p) {
  return *(const bf16x8*)p;
}

// ---------------------------------------------------------------------------
// Kernel 1: weights fp32 -> bf16, plus mask normalization.
// ---------------------------------------------------------------------------
__global__ __launch_bounds__(256) void convertW_kernel(
    const float* __restrict__ Wq, const float* __restrict__ Wk, const float* __restrict__ Wv,
    const float* __restrict__ Wr, const float* __restrict__ Wo,
    const unsigned char* __restrict__ mraw,
    short* __restrict__ W_bf, float* __restrict__ mask_f)
{
  if (blockIdx.x == 1280) {  // mask block
    __shared__ int fmis, fany;
    if (threadIdx.x == 0) { fmis = 0; fany = 0; }
    __syncthreads();
    int lm = 0, la = 0;
    for (int i = threadIdx.x; i < B_ * T_; i += 256) {
      unsigned char c = mraw[i];
      if (c) { la = 1; if (i & 3) lm = 1; }
    }
    if (lm) atomicOr(&fmis, 1);
    if (la) atomicOr(&fany, 1);
    __syncthreads();
    int mmode = fmis ? 0 : (fany ? 1 : 2);
    const int* mi = (const int*)mraw;
    for (int i = threadIdx.x; i < B_ * T_; i += 256) {
      int mv = (mmode == 0) ? (int)mraw[i] : (mmode == 1 ? mi[i] : 0);
      mask_f[i] = mv ? 1.0f : 0.0f;
    }
    return;
  }
  int gid = blockIdx.x * 256 + threadIdx.x;   // 1280*256 = 327680 f32x4 chunks
  const float* src; int base;
  if      (gid <  65536) { src = Wq; base = 0; }
  else if (gid < 131072) { src = Wk; base = 65536; }
  else if (gid < 196608) { src = Wv; base = 131072; }
  else if (gid < 262144) { src = Wr; base = 196608; }
  else                   { src = Wo; base = 262144; }
  f32x4 val = ((const f32x4*)src)[gid - base];
  short4_t o;
  o[0] = f2bf(val[0]); o[1] = f2bf(val[1]); o[2] = f2bf(val[2]); o[3] = f2bf(val[3]);
  ((short4_t*)W_bf)[gid] = o;
}

// ---------------------------------------------------------------------------
// Kernel 2: projection GEMM  C[M,512] = A[M,512] @ W[512,512]^T (+bias)
// v3 "no-drain" structure: A is reg-staged (global->reg->cvt->LDS, XOR swz);
// W fragments are loaded per-lane DIRECTLY from global (L2-resident) into
// registers — NO global_load_lds anywhere, so __syncthreads only needs
// lgkmcnt(0) and the 8 A-loads of tile it+1 stay in flight across the
// barrier (issue order: W(it) first, A(it+1) second; FIFO vmcnt keeps A
// outstanding through the MFMA phase, waited only at WRITEA).
// BM=128 BN=64 BK=64, 4 waves, full K-loop unroll (static dbuf indices),
// bijective XCD chunking. VARIANT 0: fused fp32->bf16 A (qkv+r merged).
// VARIANT 1: bf16 A (out-proj, fp32 out).
// ---------------------------------------------------------------------------
template<int VARIANT>
__global__ __launch_bounds__(256, 4) void proj_gemm(
    const float* __restrict__ qin, const float* __restrict__ kin,
    const float* __restrict__ vin, const float* __restrict__ pin,
    const short* __restrict__ W_bf, const short* __restrict__ ao_bf,
    short* __restrict__ quO, short* __restrict__ qvO, short* __restrict__ khO,
    short* __restrict__ vtO, short* __restrict__ rhO, float* __restrict__ outF,
    const float* __restrict__ bq, const float* __restrict__ bk_,
    const float* __restrict__ bv_, const float* __restrict__ bo_,
    const float* __restrict__ ub, const float* __restrict__ vb)
{
  const int bid0 = blockIdx.x;
  constexpr int PER = (VARIANT == 0) ? 160 : 32;      // blocks per XCD
  const int bid = (bid0 & 7) * PER + (bid0 >> 3);     // bijective XCD chunking

  const float* Afp = nullptr; const short* Abf = nullptr; const short* W;
  int Mtotal, mode, m0, n0;
  if constexpr (VARIANT == 0) {
    if (bid < 768) {
      int zz = bid >> 8, r2 = bid & 255;
      m0 = (r2 >> 3) * 128; n0 = (r2 & 7) * 64;
      Afp = (zz == 0) ? qin : (zz == 1) ? kin : vin;
      W = W_bf + (size_t)zz * 262144;
      Mtotal = 4096; mode = zz;
    } else {
      int r2 = bid - 768;
      m0 = (r2 >> 3) * 128; n0 = (r2 & 7) * 64;
      Afp = pin; W = W_bf + 786432;
      Mtotal = 8188; mode = 3;
    }
  } else {
    m0 = (bid >> 3) * 128; n0 = (bid & 7) * 64;
    Abf = ao_bf; W = W_bf + 1048576;
    Mtotal = 4096; mode = 4;
  }
  __shared__ __align__(16) short As[2][128 * 64];   // 32 KB total
  const int tid = threadIdx.x;
  const int lane = tid & 63, wid = tid >> 6;
  const int wr = wid >> 1, wc = wid & 1;
  const int l15 = lane & 15, l4 = lane >> 4;
  const int trow = tid >> 3;                       // 0..31 (row within round)
  const int s8 = tid & 7;                          // 16B slot within row
  const int tcolsw = ((s8 ^ (trow & 7)) << 3);     // swizzled col (elements)

  // per-lane W row pointers for the 2 B-fragments (direct-from-global)
  const short* Wp0 = W + (size_t)(n0 + wc * 32 + l15) * 512 + l4 * 8;
  const short* Wp1 = W + (size_t)(n0 + wc * 32 + 16 + l15) * 512 + l4 * 8;

  f32x4 va[4][2];     // VARIANT 0 staging regs
  bf16x8 va1[4];      // VARIANT 1 staging regs
  bf16x8 wf[2][2];    // [kf][cf] current-tile W fragments

  auto LOADA = [&](int kt) {
    if constexpr (VARIANT == 0) {
#pragma unroll
      for (int j = 0; j < 4; j++) {
        int srow = m0 + j * 32 + trow; if (srow > Mtotal - 1) srow = Mtotal - 1;
        const f32x4* p = (const f32x4*)(Afp + (size_t)srow * 512 + kt + s8 * 8);
        va[j][0] = p[0]; va[j][1] = p[1];
      }
    } else {
#pragma unroll
      for (int j = 0; j < 4; j++) {
        int srow = m0 + j * 32 + trow; if (srow > 4095) srow = 4095;
        va1[j] = ldbf8(Abf + (size_t)srow * 512 + kt + s8 * 8);
      }
    }
  };
  auto LOADW = [&](int kt) {
    wf[0][0] = ldbf8(Wp0 + kt);      wf[0][1] = ldbf8(Wp1 + kt);
    wf[1][0] = ldbf8(Wp0 + kt + 32); wf[1][1] = ldbf8(Wp1 + kt + 32);
  };
  auto WRITEA = [&](int buf) {
    if constexpr (VARIANT == 0) {
#pragma unroll
      for (int j = 0; j < 4; j++) {
        u32x4 wv;
        wv[0] = cvtpk(va[j][0][0], va[j][0][1]);
        wv[1] = cvtpk(va[j][0][2], va[j][0][3]);
        wv[2] = cvtpk(va[j][1][0], va[j][1][1]);
        wv[3] = cvtpk(va[j][1][2], va[j][1][3]);
        *(u32x4*)&As[buf][(j * 32 + trow) * 64 + tcolsw] = wv;
      }
    } else {
#pragma unroll
      for (int j = 0; j < 4; j++)
        *(bf16x8*)&As[buf][(j * 32 + trow) * 64 + tcolsw] = va1[j];
    }
  };

  f32x4 acc[4][2] = {};
  LOADA(0);
  WRITEA(0);
  __syncthreads();

#pragma unroll
  for (int it = 0; it < 8; ++it) {
    const int cur = it & 1;
    LOADW(it * 64);                 // W first (waited this iter)
    if (it < 7) LOADA((it + 1) * 64);  // A second (stays in flight past barrier)
    __builtin_amdgcn_s_setprio(1);
#pragma unroll
    for (int kf = 0; kf < 2; kf++) {
      const int colA = ((kf * 4 + l4) ^ (l15 & 7)) << 3;
      bf16x8 af[4];
#pragma unroll
      for (int rf = 0; rf < 4; rf++)
        af[rf] = ldbf8(&As[cur][(wr * 64 + rf * 16 + l15) * 64 + colA]);
#pragma unroll
      for (int rf = 0; rf < 4; rf++)
#pragma unroll
        for (int cf = 0; cf < 2; cf++)
          acc[rf][cf] = mfma16(af[rf], wf[kf][cf], acc[rf][cf]);
    }
    __builtin_amdgcn_s_setprio(0);
    if (it < 7) WRITEA(cur ^ 1);    // waits the A loads (post-MFMA)
    __syncthreads();                // lgkm drain only: no LDS-bound vmem ops
  }

#pragma unroll
  for (int cf = 0; cf < 2; cf++) {
    int n = n0 + wc * 32 + cf * 16 + l15;
    float bias = 0.f, ubv = 0.f, vbv = 0.f;
    if (mode == 0) { bias = bq[n]; ubv = ub[n]; vbv = vb[n]; }
    else if (mode == 1) bias = bk_[n];
    else if (mode == 2) bias = bv_[n];
    else if (mode == 4) bias = bo_[n];
    int hh = n >> 6, dk = n & 63;
#pragma unroll
    for (int rf = 0; rf < 4; rf++) {
#pragma unroll
      for (int reg = 0; reg < 4; reg++) {
        int m = m0 + wr * 64 + rf * 16 + l4 * 4 + reg;
        float val = acc[rf][cf][reg] + bias;
        if (mode == 0) {
          int bb = m >> 10, t = m & 1023;
          size_t ad = ((size_t)(bb * H_ + hh) * T_ + t) * DK_ + dk;
          quO[ad] = f2bf(val + ubv);
          qvO[ad] = f2bf(val + vbv);
        } else if (mode == 1) {
          int bb = m >> 10, t = m & 1023;
          khO[((size_t)(bb * H_ + hh) * T_ + t) * DK_ + dk] = f2bf(val);
        } else if (mode == 2) {
          int bb = m >> 10, t = m & 1023;
          vtO[((size_t)(bb * H_ + hh) * DK_ + dk) * T_ + t] = f2bf(val);
        } else if (mode == 3) {
          if (m < B_ * L_) {
            int bb = m / L_;
            int ll = m - bb * L_;
            rhO[((size_t)(bb * H_ + hh) * LP_ + ll) * DK_ + dk] = f2bf(val);
          }
        } else {
          outF[(size_t)m * D_ + n] = val;
        }
      }
    }
  }
}

// ---------------------------------------------------------------------------
// Kernel 3: fused relative attention, 4 waves/block, QBLK=64 (unchanged).
// ---------------------------------------------------------------------------
__global__ __launch_bounds__(256) void attn_kernel(
    const short* __restrict__ qu, const short* __restrict__ qv,
    const short* __restrict__ kh, const short* __restrict__ vt,
    const short* __restrict__ rh, const float* __restrict__ mask_f,
    short* __restrict__ attnout)
{
  const int tid = threadIdx.x;
  const int lane = tid & 63;
  const int w = tid >> 6;
  const int l15 = lane & 15, l4 = lane >> 4;
  const int bid = blockIdx.x;
  const int xcd = bid & 7, slot = bid >> 3;
  const int bh = (slot >> 4) * 8 + xcd;          // 0..31
  const int b = bh >> 3;
  const int t0b = (slot & 15) * 64;
  const int t0w = t0b + w * 16;
  const int woff = 48 - w * 16;                  // wave's band offset in Rs

  __shared__ __align__(16) short Ks[2][64 * 64];
  __shared__ __align__(16) short Vs[2][64 * 64];
  __shared__ __align__(16) short Rs[2][128 * 64];
  __shared__ __align__(16) short Ps[4][16 * 64];

  const short* kB = kh + (size_t)bh * T_ * DK_;
  const short* vB = vt + (size_t)bh * DK_ * T_;
  const short* rB = rh + (size_t)bh * LP_ * DK_;
  const float* mB = mask_f + b * T_;

  const short* quB = qu + ((size_t)bh * T_ + t0w + l15) * DK_ + l4 * 8;
  const short* qvB = qv + ((size_t)bh * T_ + t0w + l15) * DK_ + l4 * 8;
  bf16x8 quf0 = ldbf8(quB), quf1 = ldbf8(quB + 32);
  bf16x8 qvf0 = ldbf8(qvB), qvf1 = ldbf8(qvB + 32);

  const short8 ones_s = {(short)0x3F80, (short)0x3F80, (short)0x3F80, (short)0x3F80,
                         (short)0x3F80, (short)0x3F80, (short)0x3F80, (short)0x3F80};
  const bf16x8 ones8 = __builtin_bit_cast(bf16x8, ones_s);

  const int trow = tid >> 3;
  const int tcol = (((tid & 7) ^ ((tid >> 3) & 7)) << 3);
  const int wbase = w * 512;

  auto STAGE = [&](int buf, int s0) {
    const int l0b = 960 + s0 - t0b;     // block band start, in [0, 1920]
#pragma unroll
    for (int j = 0; j < 2; j++) {
      __builtin_amdgcn_global_load_lds(
          (const __attribute__((address_space(1))) unsigned int*)(kB + (size_t)(s0 + trow + j * 32) * 64 + tcol),
          (__attribute__((address_space(3))) unsigned int*)(&Ks[buf][j * 2048 + wbase]), 16, 0, 0);
      __builtin_amdgcn_global_load_lds(
          (const __attribute__((address_space(1))) unsigned int*)(vB + (size_t)(trow + j * 32) * T_ + s0 + tcol),
          (__attribute__((address_space(3))) unsigned int*)(&Vs[buf][j * 2048 + wbase]), 16, 0, 0);
    }
#pragma unroll
    for (int j = 0; j < 4; j++) {
      __builtin_amdgcn_global_load_lds(
          (const __attribute__((address_space(1))) unsigned int*)(rB + (size_t)(l0b + trow + j * 32) * 64 + tcol),
          (__attribute__((address_space(3))) unsigned int*)(&Rs[buf][j * 2048 + wbase]), 16, 0, 0);
    }
  };

  f32x4 accO[4] = {};
  f32x4 sum_acc = {};

  STAGE(0, 0);
  __syncthreads();

  const int swz = (l15 & 7) << 3;

  for (int it = 0; it < 16; ++it) {
    const int s0 = it << 6;
    const int cur = it & 1;
    if (it < 15) STAGE(cur ^ 1, s0 + 64);

    float mk[4];
#pragma unroll
    for (int cf = 0; cf < 4; cf++) mk[cf] = mB[s0 + cf * 16 + l15];

    f32x4 sacc[4] = {};
    f32x4 gacc[5] = {};
    __builtin_amdgcn_s_setprio(1);
#pragma unroll
    for (int kf = 0; kf < 2; kf++) {
      const int col = (kf * 32 + l4 * 8) ^ swz;
      bf16x8 qf = kf ? quf1 : quf0;
      bf16x8 vf_ = kf ? qvf1 : qvf0;
#pragma unroll
      for (int cf = 0; cf < 4; cf++)
        sacc[cf] = mfma16(qf, ldbf8(&Ks[cur][(cf * 16 + l15) * 64 + col]), sacc[cf]);
#pragma unroll
      for (int gf = 0; gf < 5; gf++)
        gacc[gf] = mfma16(vf_, ldbf8(&Rs[cur][(woff + gf * 16 + l15) * 64 + col]), gacc[gf]);
    }
    __builtin_amdgcn_s_setprio(0);

    float p[4][4];
#pragma unroll
    for (int r = 0; r < 4; r++) {
      const int tl = l4 * 4 + r;
      const int e = l15 + 15 - tl;               // 0..30
      const int src = (lane & 48) | (e & 15);
      float sh0 = __shfl(gacc[0][r], src);
      float sh1 = __shfl(gacc[1][r], src);
      float sh2 = __shfl(gacc[2][r], src);
      float sh3 = __shfl(gacc[3][r], src);
      float sh4 = __shfl(gacc[4][r], src);
      float ga[4] = {sh0, sh1, sh2, sh3};
      float gb[4] = {sh1, sh2, sh3, sh4};
#pragma unroll
      for (int cf = 0; cf < 4; cf++) {
        float gg = (e < 16) ? ga[cf] : gb[cf];
        float lg = (sacc[cf][r] + gg) * 0.125f;
        lg = (mk[cf] != 0.f) ? 1e-4f : lg;
        p[r][cf] = __expf(lg);                   // no max subtraction: |lg| small
      }
    }

#pragma unroll
    for (int r = 0; r < 4; r++) {
      const int tl = l4 * 4 + r;
      const int sw2 = (tl & 7) << 3;
#pragma unroll
      for (int cf = 0; cf < 4; cf++)
        Ps[w][tl * 64 + ((cf * 16 + l15) ^ sw2)] = f2bf(p[r][cf]);
    }

    __builtin_amdgcn_s_setprio(1);
#pragma unroll
    for (int kf = 0; kf < 2; kf++) {
      const int kc = kf * 32 + l4 * 8;
      bf16x8 pa = ldbf8(&Ps[w][l15 * 64 + (kc ^ swz)]);
      sum_acc = mfma16(pa, ones8, sum_acc);
#pragma unroll
      for (int vf = 0; vf < 4; vf++)
        accO[vf] = mfma16(pa, ldbf8(&Vs[cur][(vf * 16 + l15) * 64 + (kc ^ swz)]), accO[vf]);
    }
    __builtin_amdgcn_s_setprio(0);
    __syncthreads();
  }

#pragma unroll
  for (int r = 0; r < 4; r++) {
    const int tl = l4 * 4 + r;
    float inv = 1.0f / sum_acc[r];
#pragma unroll
    for (int vf = 0; vf < 4; vf++) {
      float val = accO[vf][r] * inv;
      attnout[((size_t)bh * T_ + t0w + tl) * DK_ + vf * 16 + l15] = f2bf(val);
    }
  }
}

// ---------------------------------------------------------------------------
extern "C" void kernel_launch(void* const* d_in, const int* in_sizes, int n_in,
                              void* d_out, int out_size, void* d_ws, size_t ws_size,
                              hipStream_t stream) {
  const float* qin = (const float*)d_in[0];
  const float* kin = (const float*)d_in[1];
  const float* vin = (const float*)d_in[2];
  const float* pin = (const float*)d_in[3];
  const unsigned char* mraw = (const unsigned char*)d_in[4];
  const float* Wq = (const float*)d_in[5];
  const float* bq = (const float*)d_in[6];
  const float* Wk = (const float*)d_in[7];
  const float* bk = (const float*)d_in[8];
  const float* Wv = (const float*)d_in[9];
  const float* bv = (const float*)d_in[10];
  const float* Wr = (const float*)d_in[11];
  const float* ub = (const float*)d_in[12];
  const float* vb = (const float*)d_in[13];
  const float* Wo = (const float*)d_in[14];
  const float* bo = (const float*)d_in[15];
  float* out = (float*)d_out;
  char* ws = (char*)d_ws;

  short* W_bf   = (short*)(ws + 20967424);   // Wq,Wk,Wv,Wr,Wo bf16 packed
  float* mask_f = (float*)(ws + 23588864);
  short* quW    = (short*)(ws + 23605248);   // q+bq+u  [B,H,T,DK]
  short* qvW    = (short*)(ws + 27799552);   // q+bq+v  [B,H,T,DK]
  short* khW    = (short*)(ws + 31993856);   // k       [B,H,T,DK]
  short* vtW    = (short*)(ws + 36188160);   // v^T     [B,H,DK,T]
  short* rhW    = (short*)(ws + 40382464);   // r       [B,H,2048,DK]
  short* aoW    = (short*)(ws + 48771072);   // attn out [B,H,T,DK]

  convertW_kernel<<<dim3(1281), dim3(256), 0, stream>>>(
      Wq, Wk, Wv, Wr, Wo, mraw, W_bf, mask_f);
  // merged qkv + r projections, fused fp32->bf16 A staging (1280 blocks)
  proj_gemm<0><<<dim3(1280), dim3(256), 0, stream>>>(
      qin, kin, vin, pin, W_bf, aoW, quW, qvW, khW, vtW, rhW, nullptr,
      bq, bk, bv, bo, ub, vb);
  attn_kernel<<<dim3(512), dim3(256), 0, stream>>>(
      quW, qvW, khW, vtW, rhW, mask_f, aoW);
  // output projection -> fp32 d_out (256 blocks)
  proj_gemm<1><<<dim3(256), dim3(256), 0, stream>>>(
      qin, kin, vin, pin, W_bf, aoW, quW, qvW, khW, vtW, rhW, out,
      bq, bk, bv, bo, ub, vb);
}

// Round 7
// 102.459 us; speedup vs baseline: 1.0533x; 1.0533x over previous
//
#include <hip/hip_runtime.h>
#include <stdint.h>
#include <stddef.h>

#define B_ 4
#define T_ 1024
#define D_ 512
#define H_ 8
#define DK_ 64
#define L_ 2047
#define LP_ 2048

typedef __attribute__((ext_vector_type(8))) short short8;
typedef __attribute__((ext_vector_type(4))) short short4_t;
typedef __attribute__((ext_vector_type(4))) float f32x4;
typedef __attribute__((ext_vector_type(4))) unsigned int u32x4;
typedef __attribute__((ext_vector_type(8))) __bf16 bf16x8;

static __device__ __forceinline__ short f2bf(float f) {
  union { float f; unsigned u; } x; x.f = f;
  unsigned r = x.u + 0x7fffu + ((x.u >> 16) & 1u);  // RNE
  return (short)(r >> 16);
}

static __device__ __forceinline__ f32x4 mfma16(bf16x8 a, bf16x8 b, f32x4 c) {
  return __builtin_amdgcn_mfma_f32_16x16x32_bf16(a, b, c, 0, 0, 0);
}

static __device__ __forceinline__ bf16x8 ldbf8(const short* p) {
  return *(const bf16x8*)p;
}

// ---------------------------------------------------------------------------
// Kernel 1: fp32 -> bf16 conversion of all activations+weights, packed into ws,
// plus mask normalization (robust to bool-as-u8 or int32 storage).
// ---------------------------------------------------------------------------
__global__ __launch_bounds__(256) void convert_kernel(
    const float* __restrict__ qin, const float* __restrict__ kin, const float* __restrict__ vin,
    const float* __restrict__ pin,
    const float* __restrict__ Wq, const float* __restrict__ Wk, const float* __restrict__ Wv,
    const float* __restrict__ Wr, const float* __restrict__ Wo,
    const unsigned char* __restrict__ mraw,
    short* __restrict__ dst, float* __restrict__ mask_f)
{
  if (blockIdx.x == 11518) {  // mask block
    __shared__ int fmis, fany;
    if (threadIdx.x == 0) { fmis = 0; fany = 0; }
    __syncthreads();
    int lm = 0, la = 0;
    for (int i = threadIdx.x; i < B_ * T_; i += 256) {
      unsigned char c = mraw[i];
      if (c) { la = 1; if (i & 3) lm = 1; }
    }
    if (lm) atomicOr(&fmis, 1);
    if (la) atomicOr(&fany, 1);
    __syncthreads();
    int mmode = fmis ? 0 : (fany ? 1 : 2);
    const int* mi = (const int*)mraw;
    for (int i = threadIdx.x; i < B_ * T_; i += 256) {
      int mv = (mmode == 0) ? (int)mraw[i] : (mmode == 1 ? mi[i] : 0);
      mask_f[i] = mv ? 1.0f : 0.0f;
    }
    return;
  }
  int gid = blockIdx.x * 256 + threadIdx.x;  // 11518*256 = 2948608 chunks
  const float* src; int base;
  if      (gid < 524288)  { src = qin; base = 0; }
  else if (gid < 1048576) { src = kin; base = 524288; }
  else if (gid < 1572864) { src = vin; base = 1048576; }
  else if (gid < 2620928) { src = pin; base = 1572864; }
  else if (gid < 2686464) { src = Wq;  base = 2620928; }
  else if (gid < 2752000) { src = Wk;  base = 2686464; }
  else if (gid < 2817536) { src = Wv;  base = 2752000; }
  else if (gid < 2883072) { src = Wr;  base = 2817536; }
  else                    { src = Wo;  base = 2883072; }
  f32x4 val = ((const f32x4*)src)[gid - base];
  short4_t o;
  o[0] = f2bf(val[0]); o[1] = f2bf(val[1]); o[2] = f2bf(val[2]); o[3] = f2bf(val[3]);
  ((short4_t*)dst)[gid] = o;
}

// ---------------------------------------------------------------------------
// Kernel 2: projection GEMM  C[M,512] = A[M,512] @ W[512,512]^T (+bias)
// v4 structure = round-4 gload_lds staging (A and W, XOR-swizzled source col,
// linear LDS dest, swizzled ds_read_b128) + TRIPLE-buffered LDS (prefetch
// distance 2 K-steps) + COUNTED vmcnt at the barrier (T4: s_waitcnt vmcnt(6),
// never 0 in the main loop — the newest STAGE's 6 loads stay in flight).
// Race-safety: the barrier precedes STAGE((it+2)%3); a wave passes that
// barrier only after its iter-(it-1) MFMAs consumed all ds_reads, so the
// buffer being overwritten (==(it-1)%3) is quiescent.
// BM=128 BN=64 BK=64, 4 waves, bijective XCD chunking, setprio around MFMA.
// VARIANT 0 (1280 blocks): merged qkv (bid<768, mode=bid>>8) + r (mode 3).
// VARIANT 1 (256 blocks): out-projection, fp32 out.
// ---------------------------------------------------------------------------
template<int VARIANT>
__global__ __launch_bounds__(256) void proj_gemm(
    const short* __restrict__ qkv_bf, const short* __restrict__ pos_bf,
    const short* __restrict__ W_bf, const short* __restrict__ ao_bf,
    short* __restrict__ quO, short* __restrict__ qvO, short* __restrict__ khO,
    short* __restrict__ vtO, short* __restrict__ rhO, float* __restrict__ outF,
    const float* __restrict__ bq, const float* __restrict__ bk_,
    const float* __restrict__ bv_, const float* __restrict__ bo_,
    const float* __restrict__ ub, const float* __restrict__ vb)
{
  const int bid0 = blockIdx.x;
  constexpr int PER = (VARIANT == 0) ? 160 : 32;      // blocks per XCD
  const int bid = (bid0 & 7) * PER + (bid0 >> 3);     // bijective XCD chunking

  const short* A; const short* W;
  int Mtotal, mode, m0, n0;
  if constexpr (VARIANT == 0) {
    if (bid < 768) {
      int zz = bid >> 8, r2 = bid & 255;
      m0 = (r2 >> 3) * 128; n0 = (r2 & 7) * 64;
      A = qkv_bf + (size_t)zz * 2097152; W = W_bf + (size_t)zz * 262144;
      Mtotal = 4096; mode = zz;
    } else {
      int r2 = bid - 768;
      m0 = (r2 >> 3) * 128; n0 = (r2 & 7) * 64;
      A = pos_bf; W = W_bf + 786432;
      Mtotal = 8188; mode = 3;
    }
  } else {
    m0 = (bid >> 3) * 128; n0 = (bid & 7) * 64;
    A = ao_bf; W = W_bf + 1048576;
    Mtotal = 4096; mode = 4;
  }
  __shared__ __align__(16) short As[3][128 * 64];   // 48 KB
  __shared__ __align__(16) short Bs[3][64 * 64];    // 24 KB
  const int tid = threadIdx.x;
  const int lane = tid & 63, wid = tid >> 6;
  const int wr = wid >> 1, wc = wid & 1;
  const int l15 = lane & 15, l4 = lane >> 4;
  const int trow = tid >> 3;                         // 0..31 within round
  const int tcolsw = (((tid & 7) ^ (trow & 7)) << 3); // swizzled short col
  const int wbase = wid * 512;

  auto STAGE = [&](int buf, int kt) {
#pragma unroll
    for (int j = 0; j < 4; j++) {
      int srow = m0 + j * 32 + trow; if (srow > Mtotal - 1) srow = Mtotal - 1;
      __builtin_amdgcn_global_load_lds(
          (const __attribute__((address_space(1))) unsigned int*)(A + (size_t)srow * 512 + kt + tcolsw),
          (__attribute__((address_space(3))) unsigned int*)(&As[buf][j * 2048 + wbase]), 16, 0, 0);
    }
#pragma unroll
    for (int j = 0; j < 2; j++) {
      int row = j * 32 + trow;
      __builtin_amdgcn_global_load_lds(
          (const __attribute__((address_space(1))) unsigned int*)(W + (size_t)(n0 + row) * 512 + kt + tcolsw),
          (__attribute__((address_space(3))) unsigned int*)(&Bs[buf][j * 2048 + wbase]), 16, 0, 0);
    }
  };

  f32x4 acc[4][2] = {};
  STAGE(0, 0);
  STAGE(1, 64);

#pragma unroll
  for (int it = 0; it < 8; ++it) {
    // counted-vmcnt barrier: tile `it` landed; newest STAGE stays in flight
    if (it < 7) asm volatile("s_waitcnt vmcnt(6)" ::: "memory");
    else        asm volatile("s_waitcnt vmcnt(0)" ::: "memory");
    __builtin_amdgcn_s_barrier();
    if (it < 6) STAGE((it + 2) % 3, (it + 2) * 64);  // overwrites (it-1)%3: quiescent
    const int cur = it % 3;
    __builtin_amdgcn_s_setprio(1);
#pragma unroll
    for (int kf = 0; kf < 2; kf++) {
      const int colA = ((kf * 4 + l4) ^ (l15 & 7)) << 3;
      bf16x8 af[4], bf2[2];
#pragma unroll
      for (int rf = 0; rf < 4; rf++)
        af[rf] = ldbf8(&As[cur][(wr * 64 + rf * 16 + l15) * 64 + colA]);
#pragma unroll
      for (int cf = 0; cf < 2; cf++)
        bf2[cf] = ldbf8(&Bs[cur][(wc * 32 + cf * 16 + l15) * 64 + colA]);
#pragma unroll
      for (int rf = 0; rf < 4; rf++)
#pragma unroll
        for (int cf = 0; cf < 2; cf++)
          acc[rf][cf] = mfma16(af[rf], bf2[cf], acc[rf][cf]);
    }
    __builtin_amdgcn_s_setprio(0);
  }

#pragma unroll
  for (int cf = 0; cf < 2; cf++) {
    int n = n0 + wc * 32 + cf * 16 + l15;
    float bias = 0.f, ubv = 0.f, vbv = 0.f;
    if (mode == 0) { bias = bq[n]; ubv = ub[n]; vbv = vb[n]; }
    else if (mode == 1) bias = bk_[n];
    else if (mode == 2) bias = bv_[n];
    else if (mode == 4) bias = bo_[n];
    int hh = n >> 6, dk = n & 63;
#pragma unroll
    for (int rf = 0; rf < 4; rf++) {
#pragma unroll
      for (int reg = 0; reg < 4; reg++) {
        int m = m0 + wr * 64 + rf * 16 + l4 * 4 + reg;
        float val = acc[rf][cf][reg] + bias;
        if (mode == 0) {
          int bb = m >> 10, t = m & 1023;
          size_t ad = ((size_t)(bb * H_ + hh) * T_ + t) * DK_ + dk;
          quO[ad] = f2bf(val + ubv);
          qvO[ad] = f2bf(val + vbv);
        } else if (mode == 1) {
          int bb = m >> 10, t = m & 1023;
          khO[((size_t)(bb * H_ + hh) * T_ + t) * DK_ + dk] = f2bf(val);
        } else if (mode == 2) {
          int bb = m >> 10, t = m & 1023;
          vtO[((size_t)(bb * H_ + hh) * DK_ + dk) * T_ + t] = f2bf(val);
        } else if (mode == 3) {
          if (m < B_ * L_) {
            int bb = m / L_;
            int ll = m - bb * L_;
            rhO[((size_t)(bb * H_ + hh) * LP_ + ll) * DK_ + dk] = f2bf(val);
          }
        } else {
          outF[(size_t)m * D_ + n] = val;
        }
      }
    }
  }
}

// ---------------------------------------------------------------------------
// Kernel 3: fused relative attention, 4 waves/block, QBLK=64 (unchanged).
// ---------------------------------------------------------------------------
__global__ __launch_bounds__(256) void attn_kernel(
    const short* __restrict__ qu, const short* __restrict__ qv,
    const short* __restrict__ kh, const short* __restrict__ vt,
    const short* __restrict__ rh, const float* __restrict__ mask_f,
    short* __restrict__ attnout)
{
  const int tid = threadIdx.x;
  const int lane = tid & 63;
  const int w = tid >> 6;
  const int l15 = lane & 15, l4 = lane >> 4;
  const int bid = blockIdx.x;
  const int xcd = bid & 7, slot = bid >> 3;
  const int bh = (slot >> 4) * 8 + xcd;          // 0..31
  const int b = bh >> 3;
  const int t0b = (slot & 15) * 64;
  const int t0w = t0b + w * 16;
  const int woff = 48 - w * 16;                  // wave's band offset in Rs

  __shared__ __align__(16) short Ks[2][64 * 64];
  __shared__ __align__(16) short Vs[2][64 * 64];
  __shared__ __align__(16) short Rs[2][128 * 64];
  __shared__ __align__(16) short Ps[4][16 * 64];

  const short* kB = kh + (size_t)bh * T_ * DK_;
  const short* vB = vt + (size_t)bh * DK_ * T_;
  const short* rB = rh + (size_t)bh * LP_ * DK_;
  const float* mB = mask_f + b * T_;

  const short* quB = qu + ((size_t)bh * T_ + t0w + l15) * DK_ + l4 * 8;
  const short* qvB = qv + ((size_t)bh * T_ + t0w + l15) * DK_ + l4 * 8;
  bf16x8 quf0 = ldbf8(quB), quf1 = ldbf8(quB + 32);
  bf16x8 qvf0 = ldbf8(qvB), qvf1 = ldbf8(qvB + 32);

  const short8 ones_s = {(short)0x3F80, (short)0x3F80, (short)0x3F80, (short)0x3F80,
                         (short)0x3F80, (short)0x3F80, (short)0x3F80, (short)0x3F80};
  const bf16x8 ones8 = __builtin_bit_cast(bf16x8, ones_s);

  const int trow = tid >> 3;
  const int tcol = (((tid & 7) ^ ((tid >> 3) & 7)) << 3);
  const int wbase = w * 512;

  auto STAGE = [&](int buf, int s0) {
    const int l0b = 960 + s0 - t0b;     // block band start, in [0, 1920]
#pragma unroll
    for (int j = 0; j < 2; j++) {
      __builtin_amdgcn_global_load_lds(
          (const __attribute__((address_space(1))) unsigned int*)(kB + (size_t)(s0 + trow + j * 32) * 64 + tcol),
          (__attribute__((address_space(3))) unsigned int*)(&Ks[buf][j * 2048 + wbase]), 16, 0, 0);
      __builtin_amdgcn_global_load_lds(
          (const __attribute__((address_space(1))) unsigned int*)(vB + (size_t)(trow + j * 32) * T_ + s0 + tcol),
          (__attribute__((address_space(3))) unsigned int*)(&Vs[buf][j * 2048 + wbase]), 16, 0, 0);
    }
#pragma unroll
    for (int j = 0; j < 4; j++) {
      __builtin_amdgcn_global_load_lds(
          (const __attribute__((address_space(1))) unsigned int*)(rB + (size_t)(l0b + trow + j * 32) * 64 + tcol),
          (__attribute__((address_space(3))) unsigned int*)(&Rs[buf][j * 2048 + wbase]), 16, 0, 0);
    }
  };

  f32x4 accO[4] = {};
  f32x4 sum_acc = {};

  STAGE(0, 0);
  __syncthreads();

  const int swz = (l15 & 7) << 3;

  for (int it = 0; it < 16; ++it) {
    const int s0 = it << 6;
    const int cur = it & 1;
    if (it < 15) STAGE(cur ^ 1, s0 + 64);

    float mk[4];
#pragma unroll
    for (int cf = 0; cf < 4; cf++) mk[cf] = mB[s0 + cf * 16 + l15];

    f32x4 sacc[4] = {};
    f32x4 gacc[5] = {};
    __builtin_amdgcn_s_setprio(1);
#pragma unroll
    for (int kf = 0; kf < 2; kf++) {
      const int col = (kf * 32 + l4 * 8) ^ swz;
      bf16x8 qf = kf ? quf1 : quf0;
      bf16x8 vf_ = kf ? qvf1 : qvf0;
#pragma unroll
      for (int cf = 0; cf < 4; cf++)
        sacc[cf] = mfma16(qf, ldbf8(&Ks[cur][(cf * 16 + l15) * 64 + col]), sacc[cf]);
#pragma unroll
      for (int gf = 0; gf < 5; gf++)
        gacc[gf] = mfma16(vf_, ldbf8(&Rs[cur][(woff + gf * 16 + l15) * 64 + col]), gacc[gf]);
    }
    __builtin_amdgcn_s_setprio(0);

    float p[4][4];
#pragma unroll
    for (int r = 0; r < 4; r++) {
      const int tl = l4 * 4 + r;
      const int e = l15 + 15 - tl;               // 0..30
      const int src = (lane & 48) | (e & 15);
      float sh0 = __shfl(gacc[0][r], src);
      float sh1 = __shfl(gacc[1][r], src);
      float sh2 = __shfl(gacc[2][r], src);
      float sh3 = __shfl(gacc[3][r], src);
      float sh4 = __shfl(gacc[4][r], src);
      float ga[4] = {sh0, sh1, sh2, sh3};
      float gb[4] = {sh1, sh2, sh3, sh4};
#pragma unroll
      for (int cf = 0; cf < 4; cf++) {
        float gg = (e < 16) ? ga[cf] : gb[cf];
        float lg = (sacc[cf][r] + gg) * 0.125f;
        lg = (mk[cf] != 0.f) ? 1e-4f : lg;
        p[r][cf] = __expf(lg);                   // no max subtraction: |lg| small
      }
    }

#pragma unroll
    for (int r = 0; r < 4; r++) {
      const int tl = l4 * 4 + r;
      const int sw2 = (tl & 7) << 3;
#pragma unroll
      for (int cf = 0; cf < 4; cf++)
        Ps[w][tl * 64 + ((cf * 16 + l15) ^ sw2)] = f2bf(p[r][cf]);
    }

    __builtin_amdgcn_s_setprio(1);
#pragma unroll
    for (int kf = 0; kf < 2; kf++) {
      const int kc = kf * 32 + l4 * 8;
      bf16x8 pa = ldbf8(&Ps[w][l15 * 64 + (kc ^ swz)]);
      sum_acc = mfma16(pa, ones8, sum_acc);
#pragma unroll
      for (int vf = 0; vf < 4; vf++)
        accO[vf] = mfma16(pa, ldbf8(&Vs[cur][(vf * 16 + l15) * 64 + (kc ^ swz)]), accO[vf]);
    }
    __builtin_amdgcn_s_setprio(0);
    __syncthreads();
  }

#pragma unroll
  for (int r = 0; r < 4; r++) {
    const int tl = l4 * 4 + r;
    float inv = 1.0f / sum_acc[r];
#pragma unroll
    for (int vf = 0; vf < 4; vf++) {
      float val = accO[vf][r] * inv;
      attnout[((size_t)bh * T_ + t0w + tl) * DK_ + vf * 16 + l15] = f2bf(val);
    }
  }
}

// ---------------------------------------------------------------------------
extern "C" void kernel_launch(void* const* d_in, const int* in_sizes, int n_in,
                              void* d_out, int out_size, void* d_ws, size_t ws_size,
                              hipStream_t stream) {
  const float* qin = (const float*)d_in[0];
  const float* kin = (const float*)d_in[1];
  const float* vin = (const float*)d_in[2];
  const float* pin = (const float*)d_in[3];
  const unsigned char* mraw = (const unsigned char*)d_in[4];
  const float* Wq = (const float*)d_in[5];
  const float* bq = (const float*)d_in[6];
  const float* Wk = (const float*)d_in[7];
  const float* bk = (const float*)d_in[8];
  const float* Wv = (const float*)d_in[9];
  const float* bv = (const float*)d_in[10];
  const float* Wr = (const float*)d_in[11];
  const float* ub = (const float*)d_in[12];
  const float* vb = (const float*)d_in[13];
  const float* Wo = (const float*)d_in[14];
  const float* bo = (const float*)d_in[15];
  float* out = (float*)d_out;
  char* ws = (char*)d_ws;

  short* qkv_bf = (short*)(ws + 0);          // q,k,v bf16 packed
  short* pos_bf = (short*)(ws + 12582912);   // pos bf16
  short* W_bf   = (short*)(ws + 20967424);   // Wq,Wk,Wv,Wr,Wo bf16 packed
  float* mask_f = (float*)(ws + 23588864);
  short* quW    = (short*)(ws + 23605248);   // q+bq+u  [B,H,T,DK]
  short* qvW    = (short*)(ws + 27799552);   // q+bq+v  [B,H,T,DK]
  short* khW    = (short*)(ws + 31993856);   // k       [B,H,T,DK]
  short* vtW    = (short*)(ws + 36188160);   // v^T     [B,H,DK,T]
  short* rhW    = (short*)(ws + 40382464);   // r       [B,H,2048,DK]
  short* aoW    = (short*)(ws + 48771072);   // attn out [B,H,T,DK]

  convert_kernel<<<dim3(11519), dim3(256), 0, stream>>>(
      qin, kin, vin, pin, Wq, Wk, Wv, Wr, Wo, mraw, qkv_bf, mask_f);
  // merged qkv + r projections (1280 blocks, BM=128 BN=64, counted-vmcnt)
  proj_gemm<0><<<dim3(1280), dim3(256), 0, stream>>>(
      qkv_bf, pos_bf, W_bf, aoW, quW, qvW, khW, vtW, rhW, nullptr,
      bq, bk, bv, bo, ub, vb);
  attn_kernel<<<dim3(512), dim3(256), 0, stream>>>(
      quW, qvW, khW, vtW, rhW, mask_f, aoW);
  // output projection -> fp32 d_out (256 blocks)
  proj_gemm<1><<<dim3(256), dim3(256), 0, stream>>>(
      qkv_bf, pos_bf, W_bf, aoW, quW, qvW, khW, vtW, rhW, out,
      bq, bk, bv, bo, ub, vb);
}

// Round 8
// 100.547 us; speedup vs baseline: 1.0733x; 1.0190x over previous
//
#include <hip/hip_runtime.h>
#include <stdint.h>
#include <stddef.h>

#define B_ 4
#define T_ 1024
#define D_ 512
#define H_ 8
#define DK_ 64
#define L_ 2047
#define LP_ 2048

typedef __attribute__((ext_vector_type(8))) short short8;
typedef __attribute__((ext_vector_type(4))) short short4_t;
typedef __attribute__((ext_vector_type(4))) float f32x4;
typedef __attribute__((ext_vector_type(4))) unsigned int u32x4;
typedef __attribute__((ext_vector_type(8))) __bf16 bf16x8;

static __device__ __forceinline__ short f2bf(float f) {
  union { float f; unsigned u; } x; x.f = f;
  unsigned r = x.u + 0x7fffu + ((x.u >> 16) & 1u);  // RNE
  return (short)(r >> 16);
}

static __device__ __forceinline__ f32x4 mfma16(bf16x8 a, bf16x8 b, f32x4 c) {
  return __builtin_amdgcn_mfma_f32_16x16x32_bf16(a, b, c, 0, 0, 0);
}

static __device__ __forceinline__ bf16x8 ldbf8(const short* p) {
  return *(const bf16x8*)p;
}

// ---------------------------------------------------------------------------
// Kernel 1: fp32 -> bf16 conversion of all activations+weights, packed into ws,
// plus mask normalization (robust to bool-as-u8 or int32 storage).
// ---------------------------------------------------------------------------
__global__ __launch_bounds__(256) void convert_kernel(
    const float* __restrict__ qin, const float* __restrict__ kin, const float* __restrict__ vin,
    const float* __restrict__ pin,
    const float* __restrict__ Wq, const float* __restrict__ Wk, const float* __restrict__ Wv,
    const float* __restrict__ Wr, const float* __restrict__ Wo,
    const unsigned char* __restrict__ mraw,
    short* __restrict__ dst, float* __restrict__ mask_f)
{
  if (blockIdx.x == 11518) {  // mask block
    __shared__ int fmis, fany;
    if (threadIdx.x == 0) { fmis = 0; fany = 0; }
    __syncthreads();
    int lm = 0, la = 0;
    for (int i = threadIdx.x; i < B_ * T_; i += 256) {
      unsigned char c = mraw[i];
      if (c) { la = 1; if (i & 3) lm = 1; }
    }
    if (lm) atomicOr(&fmis, 1);
    if (la) atomicOr(&fany, 1);
    __syncthreads();
    int mmode = fmis ? 0 : (fany ? 1 : 2);
    const int* mi = (const int*)mraw;
    for (int i = threadIdx.x; i < B_ * T_; i += 256) {
      int mv = (mmode == 0) ? (int)mraw[i] : (mmode == 1 ? mi[i] : 0);
      mask_f[i] = mv ? 1.0f : 0.0f;
    }
    return;
  }
  int gid = blockIdx.x * 256 + threadIdx.x;  // 11518*256 = 2948608 chunks
  const float* src; int base;
  if      (gid < 524288)  { src = qin; base = 0; }
  else if (gid < 1048576) { src = kin; base = 524288; }
  else if (gid < 1572864) { src = vin; base = 1048576; }
  else if (gid < 2620928) { src = pin; base = 1572864; }
  else if (gid < 2686464) { src = Wq;  base = 2620928; }
  else if (gid < 2752000) { src = Wk;  base = 2686464; }
  else if (gid < 2817536) { src = Wv;  base = 2752000; }
  else if (gid < 2883072) { src = Wr;  base = 2817536; }
  else                    { src = Wo;  base = 2883072; }
  f32x4 val = ((const f32x4*)src)[gid - base];
  short4_t o;
  o[0] = f2bf(val[0]); o[1] = f2bf(val[1]); o[2] = f2bf(val[2]); o[3] = f2bf(val[3]);
  ((short4_t*)dst)[gid] = o;
}

// ---------------------------------------------------------------------------
// Kernel 2: projection GEMM  C[M,512] = A[M,512] @ W[512,512]^T (+bias)
// v5 = m97-faithful fat tile: BM=128 BN=128 BK=64, 4 waves each 64x64
// (32 MFMA per phase — 2x the compute per barrier of rounds 4-7), SINGLE
// 32KB LDS buffer (4-5 blocks/CU), stage -> sync -> compute -> sync,
// XOR-swizzled staging+reads (verified 0-conflict), bijective XCD chunking.
// VARIANT 0 (640 blocks): merged qkv (bid<384) + r (bid>=384, mode 3).
// VARIANT 1 (128 blocks): out-projection, fp32 out.
// ---------------------------------------------------------------------------
template<int VARIANT>
__global__ __launch_bounds__(256, 4) void proj_gemm(
    const short* __restrict__ qkv_bf, const short* __restrict__ pos_bf,
    const short* __restrict__ W_bf, const short* __restrict__ ao_bf,
    short* __restrict__ quO, short* __restrict__ qvO, short* __restrict__ khO,
    short* __restrict__ vtO, short* __restrict__ rhO, float* __restrict__ outF,
    const float* __restrict__ bq, const float* __restrict__ bk_,
    const float* __restrict__ bv_, const float* __restrict__ bo_,
    const float* __restrict__ ub, const float* __restrict__ vb)
{
  const int bid0 = blockIdx.x;
  constexpr int PER = (VARIANT == 0) ? 80 : 16;       // blocks per XCD
  const int bid = (bid0 & 7) * PER + (bid0 >> 3);     // bijective XCD chunking

  const short* A; const short* W;
  int Mtotal, mode, m0, n0;
  if constexpr (VARIANT == 0) {
    if (bid < 384) {
      int zz = bid >> 7, r2 = bid & 127;
      m0 = (r2 >> 2) * 128; n0 = (r2 & 3) * 128;
      A = qkv_bf + (size_t)zz * 2097152; W = W_bf + (size_t)zz * 262144;
      Mtotal = 4096; mode = zz;
    } else {
      int r2 = bid - 384;
      m0 = (r2 >> 2) * 128; n0 = (r2 & 3) * 128;
      A = pos_bf; W = W_bf + 786432;
      Mtotal = 8188; mode = 3;
    }
  } else {
    m0 = (bid >> 2) * 128; n0 = (bid & 3) * 128;
    A = ao_bf; W = W_bf + 1048576;
    Mtotal = 4096; mode = 4;
  }
  __shared__ __align__(16) short As[128 * 64];   // 16 KB
  __shared__ __align__(16) short Bs[128 * 64];   // 16 KB
  const int tid = threadIdx.x;
  const int lane = tid & 63, wid = tid >> 6;
  const int wr = wid >> 1, wc = wid & 1;
  const int l15 = lane & 15, l4 = lane >> 4;
  const int trow = tid >> 3;                          // 0..31 within round
  const int tcolsw = (((tid & 7) ^ (trow & 7)) << 3); // swizzled short col

  // stage one K-tile: A[128][64] + B[128][64], 8 gload_lds per thread.
  auto STAGE = [&](int kt) {
#pragma unroll
    for (int j = 0; j < 4; j++) {
      int srow = m0 + j * 32 + trow; if (srow > Mtotal - 1) srow = Mtotal - 1;
      __builtin_amdgcn_global_load_lds(
          (const __attribute__((address_space(1))) unsigned int*)(A + (size_t)srow * 512 + kt + tcolsw),
          (__attribute__((address_space(3))) unsigned int*)(&As[(j * 32 + wid * 8) * 64]), 16, 0, 0);
    }
#pragma unroll
    for (int j = 0; j < 4; j++) {
      __builtin_amdgcn_global_load_lds(
          (const __attribute__((address_space(1))) unsigned int*)(W + (size_t)(n0 + j * 32 + trow) * 512 + kt + tcolsw),
          (__attribute__((address_space(3))) unsigned int*)(&Bs[(j * 32 + wid * 8) * 64]), 16, 0, 0);
    }
  };

  f32x4 acc[4][4] = {};

#pragma unroll
  for (int it = 0; it < 8; ++it) {
    STAGE(it * 64);
    __syncthreads();
    __builtin_amdgcn_s_setprio(1);
#pragma unroll
    for (int kf = 0; kf < 2; kf++) {
      const int colA = ((kf * 4 + l4) ^ (l15 & 7)) << 3;
      bf16x8 af[4], bf4[4];
#pragma unroll
      for (int rf = 0; rf < 4; rf++)
        af[rf] = ldbf8(&As[(wr * 64 + rf * 16 + l15) * 64 + colA]);
#pragma unroll
      for (int cf = 0; cf < 4; cf++)
        bf4[cf] = ldbf8(&Bs[(wc * 64 + cf * 16 + l15) * 64 + colA]);
#pragma unroll
      for (int rf = 0; rf < 4; rf++)
#pragma unroll
        for (int cf = 0; cf < 4; cf++)
          acc[rf][cf] = mfma16(af[rf], bf4[cf], acc[rf][cf]);
    }
    __builtin_amdgcn_s_setprio(0);
    __syncthreads();
  }

#pragma unroll
  for (int cf = 0; cf < 4; cf++) {
    int n = n0 + wc * 64 + cf * 16 + l15;
    float bias = 0.f, ubv = 0.f, vbv = 0.f;
    if (mode == 0) { bias = bq[n]; ubv = ub[n]; vbv = vb[n]; }
    else if (mode == 1) bias = bk_[n];
    else if (mode == 2) bias = bv_[n];
    else if (mode == 4) bias = bo_[n];
    int hh = n >> 6, dk = n & 63;
#pragma unroll
    for (int rf = 0; rf < 4; rf++) {
#pragma unroll
      for (int reg = 0; reg < 4; reg++) {
        int m = m0 + wr * 64 + rf * 16 + l4 * 4 + reg;
        float val = acc[rf][cf][reg] + bias;
        if (mode == 0) {
          int bb = m >> 10, t = m & 1023;
          size_t ad = ((size_t)(bb * H_ + hh) * T_ + t) * DK_ + dk;
          quO[ad] = f2bf(val + ubv);
          qvO[ad] = f2bf(val + vbv);
        } else if (mode == 1) {
          int bb = m >> 10, t = m & 1023;
          khO[((size_t)(bb * H_ + hh) * T_ + t) * DK_ + dk] = f2bf(val);
        } else if (mode == 2) {
          int bb = m >> 10, t = m & 1023;
          vtO[((size_t)(bb * H_ + hh) * DK_ + dk) * T_ + t] = f2bf(val);
        } else if (mode == 3) {
          if (m < B_ * L_) {
            int bb = m / L_;
            int ll = m - bb * L_;
            rhO[((size_t)(bb * H_ + hh) * LP_ + ll) * DK_ + dk] = f2bf(val);
          }
        } else {
          outF[(size_t)m * D_ + n] = val;
        }
      }
    }
  }
}

// ---------------------------------------------------------------------------
// Kernel 3: fused relative attention, 4 waves/block, QBLK=64 (unchanged).
// ---------------------------------------------------------------------------
__global__ __launch_bounds__(256) void attn_kernel(
    const short* __restrict__ qu, const short* __restrict__ qv,
    const short* __restrict__ kh, const short* __restrict__ vt,
    const short* __restrict__ rh, const float* __restrict__ mask_f,
    short* __restrict__ attnout)
{
  const int tid = threadIdx.x;
  const int lane = tid & 63;
  const int w = tid >> 6;
  const int l15 = lane & 15, l4 = lane >> 4;
  const int bid = blockIdx.x;
  const int xcd = bid & 7, slot = bid >> 3;
  const int bh = (slot >> 4) * 8 + xcd;          // 0..31
  const int b = bh >> 3;
  const int t0b = (slot & 15) * 64;
  const int t0w = t0b + w * 16;
  const int woff = 48 - w * 16;                  // wave's band offset in Rs

  __shared__ __align__(16) short Ks[2][64 * 64];
  __shared__ __align__(16) short Vs[2][64 * 64];
  __shared__ __align__(16) short Rs[2][128 * 64];
  __shared__ __align__(16) short Ps[4][16 * 64];

  const short* kB = kh + (size_t)bh * T_ * DK_;
  const short* vB = vt + (size_t)bh * DK_ * T_;
  const short* rB = rh + (size_t)bh * LP_ * DK_;
  const float* mB = mask_f + b * T_;

  const short* quB = qu + ((size_t)bh * T_ + t0w + l15) * DK_ + l4 * 8;
  const short* qvB = qv + ((size_t)bh * T_ + t0w + l15) * DK_ + l4 * 8;
  bf16x8 quf0 = ldbf8(quB), quf1 = ldbf8(quB + 32);
  bf16x8 qvf0 = ldbf8(qvB), qvf1 = ldbf8(qvB + 32);

  const short8 ones_s = {(short)0x3F80, (short)0x3F80, (short)0x3F80, (short)0x3F80,
                         (short)0x3F80, (short)0x3F80, (short)0x3F80, (short)0x3F80};
  const bf16x8 ones8 = __builtin_bit_cast(bf16x8, ones_s);

  const int trow = tid >> 3;
  const int tcol = (((tid & 7) ^ ((tid >> 3) & 7)) << 3);
  const int wbase = w * 512;

  auto STAGE = [&](int buf, int s0) {
    const int l0b = 960 + s0 - t0b;     // block band start, in [0, 1920]
#pragma unroll
    for (int j = 0; j < 2; j++) {
      __builtin_amdgcn_global_load_lds(
          (const __attribute__((address_space(1))) unsigned int*)(kB + (size_t)(s0 + trow + j * 32) * 64 + tcol),
          (__attribute__((address_space(3))) unsigned int*)(&Ks[buf][j * 2048 + wbase]), 16, 0, 0);
      __builtin_amdgcn_global_load_lds(
          (const __attribute__((address_space(1))) unsigned int*)(vB + (size_t)(trow + j * 32) * T_ + s0 + tcol),
          (__attribute__((address_space(3))) unsigned int*)(&Vs[buf][j * 2048 + wbase]), 16, 0, 0);
    }
#pragma unroll
    for (int j = 0; j < 4; j++) {
      __builtin_amdgcn_global_load_lds(
          (const __attribute__((address_space(1))) unsigned int*)(rB + (size_t)(l0b + trow + j * 32) * 64 + tcol),
          (__attribute__((address_space(3))) unsigned int*)(&Rs[buf][j * 2048 + wbase]), 16, 0, 0);
    }
  };

  f32x4 accO[4] = {};
  f32x4 sum_acc = {};

  STAGE(0, 0);
  __syncthreads();

  const int swz = (l15 & 7) << 3;

  for (int it = 0; it < 16; ++it) {
    const int s0 = it << 6;
    const int cur = it & 1;
    if (it < 15) STAGE(cur ^ 1, s0 + 64);

    float mk[4];
#pragma unroll
    for (int cf = 0; cf < 4; cf++) mk[cf] = mB[s0 + cf * 16 + l15];

    f32x4 sacc[4] = {};
    f32x4 gacc[5] = {};
    __builtin_amdgcn_s_setprio(1);
#pragma unroll
    for (int kf = 0; kf < 2; kf++) {
      const int col = (kf * 32 + l4 * 8) ^ swz;
      bf16x8 qf = kf ? quf1 : quf0;
      bf16x8 vf_ = kf ? qvf1 : qvf0;
#pragma unroll
      for (int cf = 0; cf < 4; cf++)
        sacc[cf] = mfma16(qf, ldbf8(&Ks[cur][(cf * 16 + l15) * 64 + col]), sacc[cf]);
#pragma unroll
      for (int gf = 0; gf < 5; gf++)
        gacc[gf] = mfma16(vf_, ldbf8(&Rs[cur][(woff + gf * 16 + l15) * 64 + col]), gacc[gf]);
    }
    __builtin_amdgcn_s_setprio(0);

    float p[4][4];
#pragma unroll
    for (int r = 0; r < 4; r++) {
      const int tl = l4 * 4 + r;
      const int e = l15 + 15 - tl;               // 0..30
      const int src = (lane & 48) | (e & 15);
      float sh0 = __shfl(gacc[0][r], src);
      float sh1 = __shfl(gacc[1][r], src);
      float sh2 = __shfl(gacc[2][r], src);
      float sh3 = __shfl(gacc[3][r], src);
      float sh4 = __shfl(gacc[4][r], src);
      float ga[4] = {sh0, sh1, sh2, sh3};
      float gb[4] = {sh1, sh2, sh3, sh4};
#pragma unroll
      for (int cf = 0; cf < 4; cf++) {
        float gg = (e < 16) ? ga[cf] : gb[cf];
        float lg = (sacc[cf][r] + gg) * 0.125f;
        lg = (mk[cf] != 0.f) ? 1e-4f : lg;
        p[r][cf] = __expf(lg);                   // no max subtraction: |lg| small
      }
    }

#pragma unroll
    for (int r = 0; r < 4; r++) {
      const int tl = l4 * 4 + r;
      const int sw2 = (tl & 7) << 3;
#pragma unroll
      for (int cf = 0; cf < 4; cf++)
        Ps[w][tl * 64 + ((cf * 16 + l15) ^ sw2)] = f2bf(p[r][cf]);
    }

    __builtin_amdgcn_s_setprio(1);
#pragma unroll
    for (int kf = 0; kf < 2; kf++) {
      const int kc = kf * 32 + l4 * 8;
      bf16x8 pa = ldbf8(&Ps[w][l15 * 64 + (kc ^ swz)]);
      sum_acc = mfma16(pa, ones8, sum_acc);
#pragma unroll
      for (int vf = 0; vf < 4; vf++)
        accO[vf] = mfma16(pa, ldbf8(&Vs[cur][(vf * 16 + l15) * 64 + (kc ^ swz)]), accO[vf]);
    }
    __builtin_amdgcn_s_setprio(0);
    __syncthreads();
  }

#pragma unroll
  for (int r = 0; r < 4; r++) {
    const int tl = l4 * 4 + r;
    float inv = 1.0f / sum_acc[r];
#pragma unroll
    for (int vf = 0; vf < 4; vf++) {
      float val = accO[vf][r] * inv;
      attnout[((size_t)bh * T_ + t0w + tl) * DK_ + vf * 16 + l15] = f2bf(val);
    }
  }
}

// ---------------------------------------------------------------------------
extern "C" void kernel_launch(void* const* d_in, const int* in_sizes, int n_in,
                              void* d_out, int out_size, void* d_ws, size_t ws_size,
                              hipStream_t stream) {
  const float* qin = (const float*)d_in[0];
  const float* kin = (const float*)d_in[1];
  const float* vin = (const float*)d_in[2];
  const float* pin = (const float*)d_in[3];
  const unsigned char* mraw = (const unsigned char*)d_in[4];
  const float* Wq = (const float*)d_in[5];
  const float* bq = (const float*)d_in[6];
  const float* Wk = (const float*)d_in[7];
  const float* bk = (const float*)d_in[8];
  const float* Wv = (const float*)d_in[9];
  const float* bv = (const float*)d_in[10];
  const float* Wr = (const float*)d_in[11];
  const float* ub = (const float*)d_in[12];
  const float* vb = (const float*)d_in[13];
  const float* Wo = (const float*)d_in[14];
  const float* bo = (const float*)d_in[15];
  float* out = (float*)d_out;
  char* ws = (char*)d_ws;

  short* qkv_bf = (short*)(ws + 0);          // q,k,v bf16 packed
  short* pos_bf = (short*)(ws + 12582912);   // pos bf16
  short* W_bf   = (short*)(ws + 20967424);   // Wq,Wk,Wv,Wr,Wo bf16 packed
  float* mask_f = (float*)(ws + 23588864);
  short* quW    = (short*)(ws + 23605248);   // q+bq+u  [B,H,T,DK]
  short* qvW    = (short*)(ws + 27799552);   // q+bq+v  [B,H,T,DK]
  short* khW    = (short*)(ws + 31993856);   // k       [B,H,T,DK]
  short* vtW    = (short*)(ws + 36188160);   // v^T     [B,H,DK,T]
  short* rhW    = (short*)(ws + 40382464);   // r       [B,H,2048,DK]
  short* aoW    = (short*)(ws + 48771072);   // attn out [B,H,T,DK]

  convert_kernel<<<dim3(11519), dim3(256), 0, stream>>>(
      qin, kin, vin, pin, Wq, Wk, Wv, Wr, Wo, mraw, qkv_bf, mask_f);
  // merged qkv + r projections (640 blocks, BM=128 BN=128, single-buffer)
  proj_gemm<0><<<dim3(640), dim3(256), 0, stream>>>(
      qkv_bf, pos_bf, W_bf, aoW, quW, qvW, khW, vtW, rhW, nullptr,
      bq, bk, bv, bo, ub, vb);
  attn_kernel<<<dim3(512), dim3(256), 0, stream>>>(
      quW, qvW, khW, vtW, rhW, mask_f, aoW);
  // output projection -> fp32 d_out (128 blocks)
  proj_gemm<1><<<dim3(128), dim3(256), 0, stream>>>(
      qkv_bf, pos_bf, W_bf, aoW, quW, qvW, khW, vtW, rhW, out,
      bq, bk, bv, bo, ub, vb);
}